// Round 3
// baseline (15334.428 us; speedup 1.0000x reference)
//
#include <hip/hip_runtime.h>

// (T,B,N,D) = (32,16,2048,64)
constexpr int T = 32;
constexpr int NROWS = 16 * 2048;     // B*N
constexpr int D = 64;
constexpr long DYN = (long)T * NROWS * D;
constexpr long FIN = (long)NROWS * D;

typedef float vf4 __attribute__((ext_vector_type(4)));

// Block = 256 threads = 4 fully independent waves (no __syncthreads at all).
// Each wave owns 16 rows for the whole time loop; lane j = feature/output col.
// Weights: w1[k][lane] in 128 VGPRs (loaded once; k indices all compile-time).
// x = [h | s] per row in a per-wave LDS slab (double-buffered), consumed by
// wave-uniform ds_read_b128 broadcasts in the GEMV. All global stores are
// lane-consecutive -> 256B full-line writes (no partial-line amplification).

constexpr int ROWSTRIDE = 132;        // dwords: 16B-aligned, bank-staggered
constexpr int XWDW = 16 * ROWSTRIDE;  // dwords per buffer per wave

__global__ __launch_bounds__(256, 2) void evo_kernel(
    const float* __restrict__ stat,   // [T][NROWS][D]
    const float* __restrict__ thre,   // [T][NROWS]
    const float* __restrict__ h0,     // [NROWS][D]
    const float* __restrict__ w1,     // [128][64]
    float* __restrict__ out)          // all_dyn | final | diffs
{
    __shared__ float xw_all[4][2][XWDW];   // ~66 KB
    __shared__ float th_all[4][2][16];

    const int tid  = threadIdx.x;
    const int lane = tid & 63;
    const int wv   = __builtin_amdgcn_readfirstlane(tid >> 6);
    const int row0 = blockIdx.x * 64 + wv * 16;

    float (*xw)[XWDW] = xw_all[wv];
    float (*th)[16]   = th_all[wv];

    // ---- weights -> 128 VGPRs (coalesced 256B per load) ----
    float w[128];
#pragma unroll
    for (int k = 0; k < 128; ++k) w[k] = w1[k * 64 + lane];

    // ---- h0 -> regs; emit all_dyn[0] ----
    float h[16];
#pragma unroll
    for (int i = 0; i < 16; ++i) {
        h[i] = h0[(long)(row0 + i) * D + lane];
        __builtin_nontemporal_store(h[i], out + (long)(row0 + i) * D + lane);
    }

    auto load_s = [&](int tt, vf4* sreg) {
        const vf4* sp = (const vf4*)(stat + ((long)tt * NROWS + row0) * D);
#pragma unroll
        for (int c = 0; c < 4; ++c)
            sreg[c] = __builtin_nontemporal_load(sp + c * 64 + lane);
    };
    auto store_s = [&](int buf, const vf4* sreg) {
#pragma unroll
        for (int c = 0; c < 4; ++c) {
            int f  = c * 256 + lane * 4;     // flat dword in 16x64 tile
            int rr = f >> 6, dd = f & 63;
            *(vf4*)&xw[buf][rr * ROWSTRIDE + 64 + dd] = sreg[c];
        }
    };
    auto load_t = [&](int tt) -> float {
        float v = 0.f;
        if (lane < 16) v = thre[(long)tt * NROWS + row0 + lane];
        return v;
    };
    auto store_t = [&](int buf, float v) {
        if (lane < 16) th[buf][lane] = v;
    };

    // ---- prologue: populate buffers for tt=1, prefetch tt=2 ----
    vf4 sreg[4];
    float treg;
    load_s(1, sreg); treg = load_t(1);
    store_s(1, sreg); store_t(1, treg);
#pragma unroll
    for (int i = 0; i < 16; ++i) xw[1][i * ROWSTRIDE + lane] = h[i];
    load_s(2, sreg); treg = load_t(2);

#pragma unroll 1
    for (int tt = 1; tt < T; ++tt) {
        const int p = tt & 1;

        // write prefetched s/thre for tt+1; issue prefetch for tt+2
        if (tt + 1 < T) { store_s(p ^ 1, sreg); store_t(p ^ 1, treg); }
        if (tt + 2 < T) { load_s(tt + 2, sreg); treg = load_t(tt + 2); }

        // ---- GEMV: z[i] = sum_k x[i][k] * w[k][lane] ----
        float z[16];
#pragma unroll
        for (int i = 0; i < 16; ++i) z[i] = 0.f;
#pragma unroll
        for (int kq = 0; kq < 32; ++kq) {
#pragma unroll
            for (int g = 0; g < 2; ++g) {
                vf4 xq[8];
#pragma unroll
                for (int i = 0; i < 8; ++i)
                    xq[i] = *(const vf4*)&xw[p][(g * 8 + i) * ROWSTRIDE + kq * 4];
#pragma unroll
                for (int e = 0; e < 4; ++e)
#pragma unroll
                    for (int i = 0; i < 8; ++i)
                        z[g * 8 + i] = fmaf(xq[i][e], w[kq * 4 + e], z[g * 8 + i]);
            }
        }

        // ---- gate + sigmoid + full-line stores ----
        float* od = out + ((long)tt * NROWS + row0) * D + lane;
        float* dd = out + DYN + FIN + ((long)(tt - 1) * NROWS + row0) * D + lane;
#pragma unroll
        for (int i = 0; i < 16; ++i) {
            float t  = th[p][i];                      // uniform LDS broadcast
            float v  = fmaf(t, z[i] - h[i], h[i]);    // z*t + h*(1-t)
            float hn = 1.0f / (1.0f + __expf(-v));
            float df = hn - h[i];
            h[i] = hn;
            __builtin_nontemporal_store(hn, od + (long)i * D);
            __builtin_nontemporal_store(df, dd + (long)i * D);
            if (tt + 1 < T) xw[p ^ 1][i * ROWSTRIDE + lane] = hn;
        }
        if (tt == T - 1) {
#pragma unroll
            for (int i = 0; i < 16; ++i)
                __builtin_nontemporal_store(h[i], out + DYN + (long)(row0 + i) * D + lane);
        }
    }
}

extern "C" void kernel_launch(void* const* d_in, const int* in_sizes, int n_in,
                              void* d_out, int out_size, void* d_ws, size_t ws_size,
                              hipStream_t stream) {
    const float* stat = (const float*)d_in[0];
    const float* thre = (const float*)d_in[1];
    const float* h0   = (const float*)d_in[2];
    const float* w1   = (const float*)d_in[3];
    float* out = (float*)d_out;

    dim3 grid(NROWS / 64);   // 512 blocks, 2 per CU
    dim3 block(256);
    evo_kernel<<<grid, block, 0, stream>>>(stat, thre, h0, w1, out);
}

// Round 4
// 12682.021 us; speedup vs baseline: 1.2091x; 1.2091x over previous
//
#include <hip/hip_runtime.h>

// (T,B,N,D) = (32,16,2048,64)
constexpr int T = 32;
constexpr int NROWS = 16 * 2048;     // B*N
constexpr int D = 64;
constexpr long DYN = (long)T * NROWS * D;
constexpr long FIN = (long)NROWS * D;

typedef float vf4 __attribute__((ext_vector_type(4)));

// One wave (64 threads) per block; each wave owns 16 rows for the whole time
// loop. lane = feature/output column. Weights w1[k][lane] live in 128 VGPRs
// (loaded once). x = [h | s] staged in per-block LDS double buffers:
//   - writes are per-lane consecutive (conflict-free)
//   - GEMV reads are wave-uniform ds_read_b128 broadcasts (conflict-free)
// No __syncthreads anywhere (single wave). All global stores lane-consecutive
// -> full 256B lines. VGPR budget ~200 < 256 cap (launch_bounds 64,2).

__global__ __launch_bounds__(64, 2) void evo_kernel(
    const float* __restrict__ stat,   // [T][NROWS][D]
    const float* __restrict__ thre,   // [T][NROWS]
    const float* __restrict__ h0,     // [NROWS][D]
    const float* __restrict__ w1,     // [128][64]
    float* __restrict__ out)          // all_dyn | final | diffs
{
    __shared__ float hb[2][16][64];   // 8 KB: h double buffer
    __shared__ float sb[2][16][64];   // 8 KB: s double buffer

    const int lane = threadIdx.x;     // 0..63
    const int row0 = blockIdx.x * 16;

    // ---- weights -> 128 VGPRs (coalesced 256B per load, one time) ----
    float w[128];
#pragma unroll
    for (int k = 0; k < 128; ++k) w[k] = w1[k * 64 + lane];

    // ---- h0 -> regs + LDS(buf1) ; emit all_dyn[0] ----
    float h[16];
#pragma unroll
    for (int i = 0; i < 16; ++i) {
        h[i] = h0[(long)(row0 + i) * D + lane];
        __builtin_nontemporal_store(h[i], out + (long)(row0 + i) * D + lane);
        hb[1][i][lane] = h[i];
    }

    // ---- s(1) -> LDS buf1 (via regs); prefetch s(2) into sreg ----
    vf4 sreg[4];
    {
        const vf4* sp1 = (const vf4*)(stat + ((long)1 * NROWS + row0) * D);
#pragma unroll
        for (int c = 0; c < 4; ++c) sreg[c] = __builtin_nontemporal_load(sp1 + c * 64 + lane);
#pragma unroll
        for (int c = 0; c < 4; ++c) ((vf4*)&sb[1][0][0])[c * 64 + lane] = sreg[c];
        const vf4* sp2 = (const vf4*)(stat + ((long)2 * NROWS + row0) * D);
#pragma unroll
        for (int c = 0; c < 4; ++c) sreg[c] = __builtin_nontemporal_load(sp2 + c * 64 + lane);
    }

#pragma unroll 1
    for (int tt = 1; tt < T; ++tt) {
        const int p = tt & 1;

        // stage prefetched s(tt+1) into the other buffer; prefetch s(tt+2)
        if (tt + 1 < T) {
#pragma unroll
            for (int c = 0; c < 4; ++c) ((vf4*)&sb[p ^ 1][0][0])[c * 64 + lane] = sreg[c];
        }
        if (tt + 2 < T) {
            const vf4* sp = (const vf4*)(stat + ((long)(tt + 2) * NROWS + row0) * D);
#pragma unroll
            for (int c = 0; c < 4; ++c) sreg[c] = __builtin_nontemporal_load(sp + c * 64 + lane);
        }

        const float* tp = thre + (long)tt * NROWS + row0;   // uniform -> scalar loads

        // ---- GEMV: z[i][lane] = sum_k x[i][k] * w[k][lane] ----
        float z[16];
#pragma unroll
        for (int i = 0; i < 16; ++i) z[i] = 0.f;
#pragma unroll
        for (int i = 0; i < 16; ++i) {
#pragma unroll
            for (int kq = 0; kq < 16; ++kq) {
                vf4 xh = *(const vf4*)&hb[p][i][kq * 4];   // uniform broadcast
                vf4 xv = *(const vf4*)&sb[p][i][kq * 4];   // uniform broadcast
#pragma unroll
                for (int e = 0; e < 4; ++e) {
                    z[i] = fmaf(xh[e], w[kq * 4 + e],      z[i]);
                    z[i] = fmaf(xv[e], w[64 + kq * 4 + e], z[i]);
                }
            }
        }

        // ---- gate + sigmoid + full-line stores ----
        float* od = out + ((long)tt * NROWS + row0) * D + lane;
        float* dd = out + DYN + FIN + ((long)(tt - 1) * NROWS + row0) * D + lane;
#pragma unroll
        for (int i = 0; i < 16; ++i) {
            float t  = tp[i];                          // uniform
            float v  = fmaf(t, z[i] - h[i], h[i]);     // z*t + h*(1-t)
            float hn = 1.0f / (1.0f + __expf(-v));
            float df = hn - h[i];
            h[i] = hn;
            __builtin_nontemporal_store(hn, od + (long)i * D);
            __builtin_nontemporal_store(df, dd + (long)i * D);
            if (tt + 1 < T) hb[p ^ 1][i][lane] = hn;
        }
        if (tt == T - 1) {
#pragma unroll
            for (int i = 0; i < 16; ++i)
                __builtin_nontemporal_store(h[i], out + DYN + (long)(row0 + i) * D + lane);
        }
    }
}

extern "C" void kernel_launch(void* const* d_in, const int* in_sizes, int n_in,
                              void* d_out, int out_size, void* d_ws, size_t ws_size,
                              hipStream_t stream) {
    const float* stat = (const float*)d_in[0];
    const float* thre = (const float*)d_in[1];
    const float* h0   = (const float*)d_in[2];
    const float* w1   = (const float*)d_in[3];
    float* out = (float*)d_out;

    dim3 grid(NROWS / 16);   // 2048 one-wave blocks -> 2 waves/SIMD
    dim3 block(64);
    evo_kernel<<<grid, block, 0, stream>>>(stat, thre, h0, w1, out);
}

// Round 5
// 12670.149 us; speedup vs baseline: 1.2103x; 1.0009x over previous
//
#include <hip/hip_runtime.h>

// (T,B,N,D) = (32,16,2048,64)
constexpr int T = 32;
constexpr int NROWS = 16 * 2048;     // B*N
constexpr int D = 64;
constexpr long DYN = (long)T * NROWS * D;
constexpr long FIN = (long)NROWS * D;

typedef float vf4 __attribute__((ext_vector_type(4)));

// One wave (64 threads) per block; each wave owns 16 rows for the whole time
// loop. lane = feature/output column. Weights w1[k][lane] live in 128 VGPRs
// (loaded once). x = [h | s] staged in per-block LDS double buffers:
//   - writes are per-lane consecutive (conflict-free)
//   - GEMV reads are wave-uniform ds_read_b128 broadcasts (conflict-free)
// No __syncthreads (single wave). All global stores lane-consecutive ->
// full 256B lines.
//
// amdgpu_waves_per_eu(2,2): pin allocator occupancy target to exactly 2
// waves/EU -> 256-VGPR budget. R3/R4 showed that launch_bounds alone lets
// the allocator cap at 128 VGPRs and spill w[]/z[] to scratch (44 GB of
// scratch traffic, 12.7 ms).

__global__ __launch_bounds__(64)
__attribute__((amdgpu_waves_per_eu(2, 2)))
void evo_kernel(
    const float* __restrict__ stat,   // [T][NROWS][D]
    const float* __restrict__ thre,   // [T][NROWS]
    const float* __restrict__ h0,     // [NROWS][D]
    const float* __restrict__ w1,     // [128][64]
    float* __restrict__ out)          // all_dyn | final | diffs
{
    __shared__ float hb[2][16][64];   // 8 KB: h double buffer
    __shared__ float sb[2][16][64];   // 8 KB: s double buffer

    const int lane = threadIdx.x;     // 0..63
    const int row0 = blockIdx.x * 16;

    // ---- weights -> 128 VGPRs (coalesced 256B per load, one time) ----
    float w[128];
#pragma unroll
    for (int k = 0; k < 128; ++k) w[k] = w1[k * 64 + lane];

    // ---- h0 -> regs + LDS(buf1) ; emit all_dyn[0] ----
    float h[16];
#pragma unroll
    for (int i = 0; i < 16; ++i) {
        h[i] = h0[(long)(row0 + i) * D + lane];
        __builtin_nontemporal_store(h[i], out + (long)(row0 + i) * D + lane);
        hb[1][i][lane] = h[i];
    }

    // ---- s(1) -> LDS buf1 (via regs); prefetch s(2) into sreg ----
    vf4 sreg[4];
    {
        const vf4* sp1 = (const vf4*)(stat + ((long)1 * NROWS + row0) * D);
#pragma unroll
        for (int c = 0; c < 4; ++c) sreg[c] = __builtin_nontemporal_load(sp1 + c * 64 + lane);
#pragma unroll
        for (int c = 0; c < 4; ++c) ((vf4*)&sb[1][0][0])[c * 64 + lane] = sreg[c];
        const vf4* sp2 = (const vf4*)(stat + ((long)2 * NROWS + row0) * D);
#pragma unroll
        for (int c = 0; c < 4; ++c) sreg[c] = __builtin_nontemporal_load(sp2 + c * 64 + lane);
    }

#pragma unroll 1
    for (int tt = 1; tt < T; ++tt) {
        const int p = tt & 1;

        // stage prefetched s(tt+1) into the other buffer; prefetch s(tt+2)
        if (tt + 1 < T) {
#pragma unroll
            for (int c = 0; c < 4; ++c) ((vf4*)&sb[p ^ 1][0][0])[c * 64 + lane] = sreg[c];
        }
        if (tt + 2 < T) {
            const vf4* sp = (const vf4*)(stat + ((long)(tt + 2) * NROWS + row0) * D);
#pragma unroll
            for (int c = 0; c < 4; ++c) sreg[c] = __builtin_nontemporal_load(sp + c * 64 + lane);
        }

        const float* tp = thre + (long)tt * NROWS + row0;   // uniform -> scalar loads

        // ---- GEMV: z[i][lane] = sum_k x[i][k] * w[k][lane] ----
        float z[16];
#pragma unroll
        for (int i = 0; i < 16; ++i) z[i] = 0.f;
#pragma unroll
        for (int i = 0; i < 16; ++i) {
#pragma unroll
            for (int kq = 0; kq < 16; ++kq) {
                vf4 xh = *(const vf4*)&hb[p][i][kq * 4];   // uniform broadcast
                vf4 xv = *(const vf4*)&sb[p][i][kq * 4];   // uniform broadcast
#pragma unroll
                for (int e = 0; e < 4; ++e) {
                    z[i] = fmaf(xh[e], w[kq * 4 + e],      z[i]);
                    z[i] = fmaf(xv[e], w[64 + kq * 4 + e], z[i]);
                }
            }
        }

        // ---- gate + sigmoid + full-line stores ----
        float* od = out + ((long)tt * NROWS + row0) * D + lane;
        float* dd = out + DYN + FIN + ((long)(tt - 1) * NROWS + row0) * D + lane;
#pragma unroll
        for (int i = 0; i < 16; ++i) {
            float t  = tp[i];                          // uniform
            float v  = fmaf(t, z[i] - h[i], h[i]);     // z*t + h*(1-t)
            float hn = 1.0f / (1.0f + __expf(-v));
            float df = hn - h[i];
            h[i] = hn;
            __builtin_nontemporal_store(hn, od + (long)i * D);
            __builtin_nontemporal_store(df, dd + (long)i * D);
            if (tt + 1 < T) hb[p ^ 1][i][lane] = hn;
        }
        if (tt == T - 1) {
#pragma unroll
            for (int i = 0; i < 16; ++i)
                __builtin_nontemporal_store(h[i], out + DYN + (long)(row0 + i) * D + lane);
        }
    }
}

extern "C" void kernel_launch(void* const* d_in, const int* in_sizes, int n_in,
                              void* d_out, int out_size, void* d_ws, size_t ws_size,
                              hipStream_t stream) {
    const float* stat = (const float*)d_in[0];
    const float* thre = (const float*)d_in[1];
    const float* h0   = (const float*)d_in[2];
    const float* w1   = (const float*)d_in[3];
    float* out = (float*)d_out;

    dim3 grid(NROWS / 16);   // 2048 one-wave blocks -> 8 waves/CU = 2/SIMD
    dim3 block(64);
    evo_kernel<<<grid, block, 0, stream>>>(stat, thre, h0, w1, out);
}

// Round 6
// 471.858 us; speedup vs baseline: 32.4979x; 26.8516x over previous
//
#include <hip/hip_runtime.h>

// (T,B,N,D) = (32,16,2048,64)
constexpr int T = 32;
constexpr int NROWS = 16 * 2048;     // B*N
constexpr int D = 64;
constexpr long DYN = (long)T * NROWS * D;
constexpr long FIN = (long)NROWS * D;

typedef float vf4 __attribute__((ext_vector_type(4)));
typedef float f2  __attribute__((ext_vector_type(2)));

// Direct global->LDS (16B/lane). LDS dest is wave-uniform base; HW scatters
// lane l's 16B to base + l*16 (guide §5). AS casts via uintptr (CK pattern).
__device__ __forceinline__ void gload16(const float* g, float* l) {
    __builtin_amdgcn_global_load_lds(
        (const __attribute__((address_space(1))) unsigned int*)(unsigned long long)(const void*)g,
        (__attribute__((address_space(3))) unsigned int*)(unsigned long long)(void*)l,
        16, 0, 0);
}

// 2 waves/block, 16 rows/block. lane = feature/output column.
// wv=0 (H-wave): w1[k<64] in 64 VGPRs; GEMV h-half; sigmoid/gate; all stores.
// wv=1 (S-wave): w1[k>=64]; stages s via global_load_lds (1 step ahead,
//                counted vmcnt); GEMV s-half; z_s -> LDS.
// One __syncthreads per step (z_s handoff); zb double-buffered; sb
// double-buffered (async loads); hb single (wave-private, read-then-write).
// R3-R5 lesson: allocator caps at 128 VGPRs for this kernel -> design to fit.

__global__ __launch_bounds__(128) void evo_kernel(
    const float* __restrict__ stat,   // [T][NROWS][D]
    const float* __restrict__ thre,   // [T][NROWS]
    const float* __restrict__ h0,     // [NROWS][D]
    const float* __restrict__ w1,     // [128][64]
    float* __restrict__ out)          // all_dyn | final | diffs
{
    __shared__ float hb[16][64];        // 4 KB  h state (H-wave private)
    __shared__ float sb[2][16][64];     // 8 KB  s tiles (S-wave private, dbuf)
    __shared__ float zb[2][16][64];     // 8 KB  z_s handoff (dbuf)

    const int lane = threadIdx.x & 63;
    const int wv   = __builtin_amdgcn_readfirstlane(threadIdx.x >> 6);
    const int row0 = blockIdx.x * 16;

    // ---- this wave's K-half of the weights, k-paired for v_pk_fma_f32 ----
    f2 w2[32];
    {
        const float* wb = w1 + wv * 64 * 64;
#pragma unroll
        for (int j = 0; j < 32; ++j) {
            f2 v; v.x = wb[(2 * j) * 64 + lane]; v.y = wb[(2 * j + 1) * 64 + lane];
            w2[j] = v;
        }
    }

    if (wv == 0) {
        // h0 -> LDS; emit all_dyn[0]
#pragma unroll
        for (int i = 0; i < 16; ++i) {
            float hv = h0[(long)(row0 + i) * D + lane];
            __builtin_nontemporal_store(hv, out + (long)(row0 + i) * D + lane);
            hb[i][lane] = hv;
        }
    } else {
        // issue s(1) -> sb[1]
        const float* sp = stat + ((long)1 * NROWS + row0) * D;
#pragma unroll
        for (int c = 0; c < 4; ++c)
            gload16(sp + c * 256 + lane * 4, &sb[1][0][0] + c * 256);
    }

#pragma unroll 1
    for (int tt = 1; tt < T; ++tt) {
        const int p = tt & 1;

        if (wv == 1) {
            if (tt + 1 < T) {   // prefetch s(tt+1), a full step ahead
                const float* sp = stat + ((long)(tt + 1) * NROWS + row0) * D;
#pragma unroll
                for (int c = 0; c < 4; ++c)
                    gload16(sp + c * 256 + lane * 4, &sb[p ^ 1][0][0] + c * 256);
                asm volatile("s_waitcnt vmcnt(4)" ::: "memory");  // sb[p] landed
            } else {
                asm volatile("s_waitcnt vmcnt(0)" ::: "memory");
            }
        }

        // ---- GEMV half: z2[i] = sum_k x[i][k] * w[k][lane] (pk-fma pairs) ----
        const float (*xb)[64] = (wv == 0) ? hb : sb[p];
        f2 z2[16];
#pragma unroll
        for (int i = 0; i < 16; ++i) { z2[i].x = 0.f; z2[i].y = 0.f; }
#pragma unroll
        for (int i = 0; i < 16; ++i) {
#pragma unroll
            for (int kq = 0; kq < 16; ++kq) {
                vf4 x = *(const vf4*)&xb[i][kq * 4];   // uniform broadcast read
                f2 xl; xl.x = x.x; xl.y = x.y;
                f2 xh; xh.x = x.z; xh.y = x.w;
                z2[i] = __builtin_elementwise_fma(xl, w2[2 * kq],     z2[i]);
                z2[i] = __builtin_elementwise_fma(xh, w2[2 * kq + 1], z2[i]);
            }
        }

        if (wv == 1) {
#pragma unroll
            for (int i = 0; i < 16; ++i) zb[p][i][lane] = z2[i].x + z2[i].y;
        }

        __syncthreads();   // z_s(tt) ready for H-wave

        if (wv == 0) {
            const float* tp = thre + (long)tt * NROWS + row0;    // scalar loads
            float* od = out + ((long)tt * NROWS + row0) * D + lane;
            float* dd = out + DYN + FIN + ((long)(tt - 1) * NROWS + row0) * D + lane;
#pragma unroll
            for (int i = 0; i < 16; ++i) {
                float zi  = z2[i].x + z2[i].y + zb[p][i][lane];
                float hp_ = hb[i][lane];
                float t   = tp[i];
                float v   = fmaf(t, zi - hp_, hp_);    // z*t + h*(1-t)
                float hn  = 1.0f / (1.0f + __expf(-v));
                float df  = hn - hp_;
                hb[i][lane] = hn;                       // state for next step
                __builtin_nontemporal_store(hn, od + (long)i * D);  // full 256B rows
                __builtin_nontemporal_store(df, dd + (long)i * D);
                if (tt == T - 1)
                    __builtin_nontemporal_store(hn, out + DYN + (long)(row0 + i) * D + lane);
            }
        }
    }
}

extern "C" void kernel_launch(void* const* d_in, const int* in_sizes, int n_in,
                              void* d_out, int out_size, void* d_ws, size_t ws_size,
                              hipStream_t stream) {
    const float* stat = (const float*)d_in[0];
    const float* thre = (const float*)d_in[1];
    const float* h0   = (const float*)d_in[2];
    const float* w1   = (const float*)d_in[3];
    float* out = (float*)d_out;

    dim3 grid(NROWS / 16);   // 2048 blocks -> 8 blocks/CU, 4 waves/SIMD
    dim3 block(128);
    evo_kernel<<<grid, block, 0, stream>>>(stat, thre, h0, w1, out);
}

// Round 7
// 155.583 us; speedup vs baseline: 98.5608x; 3.0328x over previous
//
#include <hip/hip_runtime.h>

// (T,B,N,D) = (32,16,2048,64)
constexpr int T = 32;
constexpr int NROWS = 16 * 2048;     // B*N
constexpr int D = 64;
constexpr long DYN = (long)T * NROWS * D;
constexpr long FIN = (long)NROWS * D;

typedef float f32x4  __attribute__((ext_vector_type(4)));
typedef short bf16x8 __attribute__((ext_vector_type(8)));   // 8 bf16 (guide §3)

// f32 -> bf16 bits, round-to-nearest-even
__device__ __forceinline__ short f2b(float f) {
    union { float f; unsigned u; } v; v.f = f;
    unsigned r = (v.u + 0x7fffu + ((v.u >> 16) & 1u)) >> 16;
    return (short)r;
}

// Block = 128 threads = 2 waves, 16 rows/block, K=128 split across waves:
//   wv=0: k<64  (h columns),  wv=1: k>=64 (s columns).
// Each wave: its w1-half as 8 bf16 B-frags (32 VGPRs, loaded once), and per
// step 8x mfma_f32_16x16x32_bf16 -> D frags -> small LDS z-buffer. s operand
// is loaded per-lane from global DIRECTLY in A-frag layout (full 128B lines,
// no LDS). h state in 4KB XOR-swizzled LDS. After barrier both waves run the
// epilogue on 8 rows each in lane=col layout -> full 256B-line stores.
// R6 lesson: LDS broadcast GEMV (256 b128/wave-step) was the bottleneck;
// MFMA does broadcast+reduce in the matrix pipe. ~90 VGPRs, no spill risk.

__global__ __launch_bounds__(128) void evo_kernel(
    const float* __restrict__ stat,   // [T][NROWS][D]
    const float* __restrict__ thre,   // [T][NROWS]
    const float* __restrict__ h0,     // [NROWS][D]
    const float* __restrict__ w1,     // [128][64]
    float* __restrict__ out)          // all_dyn | final | diffs
{
    __shared__ float hbuf[16 * 64];   // 4KB, XOR-swizzled: byte ^= (row&7)<<4
    __shared__ float zS[16][68];      // S-wave D frags (pad 68: conflict-free)
    __shared__ float zH[16][68];      // H-wave D frags

    const int lane = threadIdx.x & 63;
    const int wv   = __builtin_amdgcn_readfirstlane(threadIdx.x >> 6);
    const int row0 = blockIdx.x * 16;
    const int m = lane & 15;          // matrix-dim index (A row / B col)
    const int q = lane >> 4;          // k-group

    auto hptr = [&](int row, int col) -> float* {          // swizzled f32 addr
        int byte = ((row * 64 + col) * 4) ^ ((row & 7) << 4);
        return (float*)((char*)hbuf + byte);
    };
    auto hquad = [&](int row, int c0) -> f32x4 {           // swizzled 16B read
        int byte = ((row * 64 + c0) * 4) ^ ((row & 7) << 4);
        return *(const f32x4*)((const char*)hbuf + byte);
    };

    // ---- B-frags: w1[64*wv + 32*kc + 8*q + j][m + 16*g], one-time ----
    bf16x8 B[2][4];
    {
        const float* wb = w1 + (long)(wv * 64) * 64;
#pragma unroll
        for (int kc = 0; kc < 2; ++kc)
#pragma unroll
            for (int g = 0; g < 4; ++g) {
                bf16x8 t;
#pragma unroll
                for (int j = 0; j < 8; ++j)
                    t[j] = f2b(wb[(kc * 32 + q * 8 + j) * 64 + m + 16 * g]);
                B[kc][g] = t;
            }
    }

    // ---- prologue: h0 rows [8wv,8wv+8) -> hbuf + all_dyn[0] ----
#pragma unroll
    for (int i2 = 0; i2 < 8; ++i2) {
        int i = wv * 8 + i2;
        float hv = h0[(long)(row0 + i) * D + lane];
        __builtin_nontemporal_store(hv, out + (long)(row0 + i) * D + lane);
        *hptr(i, lane) = hv;
    }

    // ---- S-wave: prefetch s(1) per-lane in A-frag layout ----
    f32x4 sf[4];
    if (wv == 1) {
        const float* sp = stat + ((long)1 * NROWS + row0) * D;
#pragma unroll
        for (int kc = 0; kc < 2; ++kc)
#pragma unroll
            for (int hh = 0; hh < 2; ++hh)
                sf[kc * 2 + hh] = __builtin_nontemporal_load(
                    (const f32x4*)(sp + m * 64 + kc * 32 + q * 8 + hh * 4));
    }
    __syncthreads();

#pragma unroll 1
    for (int tt = 1; tt < T; ++tt) {
        // ---- A-frags ----
        bf16x8 A[2];
        if (wv == 0) {
#pragma unroll
            for (int kc = 0; kc < 2; ++kc) {
                f32x4 lo = hquad(m, kc * 32 + q * 8);
                f32x4 hi = hquad(m, kc * 32 + q * 8 + 4);
                bf16x8 a;
#pragma unroll
                for (int e = 0; e < 4; ++e) { a[e] = f2b(lo[e]); a[4 + e] = f2b(hi[e]); }
                A[kc] = a;
            }
        } else {
#pragma unroll
            for (int kc = 0; kc < 2; ++kc) {
                bf16x8 a;
#pragma unroll
                for (int e = 0; e < 4; ++e) { a[e] = f2b(sf[kc * 2][e]); a[4 + e] = f2b(sf[kc * 2 + 1][e]); }
                A[kc] = a;
            }
        }

        // ---- 8 MFMA: D[g] += A[kc] * B[kc][g] ----
        f32x4 dacc[4] = {{0.f,0.f,0.f,0.f},{0.f,0.f,0.f,0.f},{0.f,0.f,0.f,0.f},{0.f,0.f,0.f,0.f}};
#pragma unroll
        for (int g = 0; g < 4; ++g)
#pragma unroll
            for (int kc = 0; kc < 2; ++kc)
                dacc[g] = __builtin_amdgcn_mfma_f32_16x16x32_bf16(A[kc], B[kc][g], dacc[g], 0, 0, 0);

        // ---- D -> z-buffer (row = 4q+rr, col = m+16g; 2-way padded) ----
        float (*zbuf)[68] = wv ? zS : zH;
#pragma unroll
        for (int g = 0; g < 4; ++g)
#pragma unroll
            for (int rr = 0; rr < 4; ++rr)
                zbuf[q * 4 + rr][m + 16 * g] = dacc[g][rr];

        // ---- S-wave: prefetch s(tt+1) ----
        if (wv == 1 && tt + 1 < T) {
            const float* sp = stat + ((long)(tt + 1) * NROWS + row0) * D;
#pragma unroll
            for (int kc = 0; kc < 2; ++kc)
#pragma unroll
                for (int hh = 0; hh < 2; ++hh)
                    sf[kc * 2 + hh] = __builtin_nontemporal_load(
                        (const f32x4*)(sp + m * 64 + kc * 32 + q * 8 + hh * 4));
        }

        __syncthreads();   // z complete

        // ---- epilogue: rows [8wv, 8wv+8), lane = col ----
        {
            const float* tp = thre + (long)tt * NROWS + row0;
            float* od = out + ((long)tt * NROWS + row0) * D + lane;
            float* dd = out + DYN + FIN + ((long)(tt - 1) * NROWS + row0) * D + lane;
#pragma unroll
            for (int i2 = 0; i2 < 8; ++i2) {
                int i  = wv * 8 + i2;
                float z  = zS[i][lane] + zH[i][lane];
                float hp = *hptr(i, lane);
                float tg = tp[i];                        // wave-uniform scalar
                float v  = fmaf(tg, z - hp, hp);         // z*t + h*(1-t)
                float hn = 1.0f / (1.0f + __expf(-v));
                float df = hn - hp;
                *hptr(i, lane) = hn;                     // state for next step
                __builtin_nontemporal_store(hn, od + (long)i * D);
                __builtin_nontemporal_store(df, dd + (long)i * D);
                if (tt == T - 1)
                    __builtin_nontemporal_store(hn, out + DYN + (long)(row0 + i) * D + lane);
            }
        }
        __syncthreads();   // h/z consumed before next step overwrites
    }
}

extern "C" void kernel_launch(void* const* d_in, const int* in_sizes, int n_in,
                              void* d_out, int out_size, void* d_ws, size_t ws_size,
                              hipStream_t stream) {
    const float* stat = (const float*)d_in[0];
    const float* thre = (const float*)d_in[1];
    const float* h0   = (const float*)d_in[2];
    const float* w1   = (const float*)d_in[3];
    float* out = (float*)d_out;

    dim3 grid(NROWS / 16);   // 2048 blocks -> 8 blocks/CU, 16 waves/CU
    dim3 block(128);
    evo_kernel<<<grid, block, 0, stream>>>(stat, thre, h0, w1, out);
}